// Round 1
// baseline (1168.140 us; speedup 1.0000x reference)
//
#include <hip/hip_runtime.h>

// CIN: B=512, M=32, D=64, layers O=128 each, H = 32 / 128 / 128.
// out[b,o,d] = relu(bias[o] + sum_{hh,m} W[o, hh*32+m] * h[b,hh,d] * x0[b,m,d])
// res[b, off+o] = sum_d out[b,o,d];  score[b] = res[b,:] . lw + lb

constexpr int Bb = 512;
constexpr int Mm = 32;
constexpr int Dd = 64;
constexpr int Oo = 128;
constexpr int RES = 384;

template <int H>
__global__ __launch_bounds__(256, 4) void cin_layer_kernel(
    const float* __restrict__ x0,    // [B, 32, 64]
    const float* __restrict__ h_in,  // [B, H, 64]
    const float* __restrict__ W,     // [128, H*32]
    const float* __restrict__ bias,  // [128]
    float* __restrict__ h_out,       // [B, 128, 64] or nullptr
    float* __restrict__ res,         // [B, 384]
    int res_off) {
  __shared__ float h_lds[H * Dd];

  const int b = blockIdx.x;
  const int obase = blockIdx.y * 64;  // this block covers o in [obase, obase+64)
  const int tid = threadIdx.x;
  const int lane = tid & 63;
  const int wid = __builtin_amdgcn_readfirstlane(tid >> 6);  // wave-uniform

  // Stage h_in[b] into LDS (float4, coalesced). H*64 floats = 512 or 2048 f4/4.
  {
    const float4* hg = reinterpret_cast<const float4*>(h_in + (size_t)b * H * Dd);
    float4* hl = reinterpret_cast<float4*>(h_lds);
    constexpr int HV = H * Dd / 4;
#pragma unroll
    for (int i = 0; i < HV / 256; ++i) hl[tid + i * 256] = hg[tid + i * 256];
  }

  // x0[b, m, lane] in registers (32 VGPR/lane), coalesced dword loads.
  float xr[Mm];
  {
    const float* xg = x0 + (size_t)b * Mm * Dd + lane;
#pragma unroll
    for (int m = 0; m < Mm; ++m) xr[m] = xg[m * Dd];
  }

  __syncthreads();

  // Each wave handles 16 consecutive-ish o values; o is wave-uniform so the
  // W row reads become scalar (s_load) traffic, leaving VALU to pure FMA.
#pragma unroll 1
  for (int j = 0; j < 16; ++j) {
    const int o = obase + wid * 16 + j;
    const float* __restrict__ Wrow = W + (size_t)o * (H * Mm);

    float acc0 = 0.f, acc1 = 0.f;
#pragma unroll 4
    for (int hh = 0; hh < H; ++hh) {
      const float hv = h_lds[hh * Dd + lane];
      float w0 = 0.f, w1 = 0.f;
#pragma unroll
      for (int m = 0; m < Mm; m += 2) {
        w0 = fmaf(Wrow[hh * Mm + m + 0], xr[m + 0], w0);
        w1 = fmaf(Wrow[hh * Mm + m + 1], xr[m + 1], w1);
      }
      acc0 = fmaf(w0, hv, acc0);
      acc1 = fmaf(w1, hv, acc1);
    }

    float v = acc0 + acc1 + bias[o];
    v = v > 0.f ? v : 0.f;

    if (h_out != nullptr) h_out[((size_t)b * Oo + o) * Dd + lane] = v;

    // row-sum over d (64 lanes) for the final linear
    float s = v;
#pragma unroll
    for (int off = 32; off >= 1; off >>= 1) s += __shfl_xor(s, off, 64);
    if (lane == 0) res[b * RES + res_off + o] = s;
  }
}

__global__ __launch_bounds__(64) void cin_score_kernel(
    const float* __restrict__ res,  // [B, 384]
    const float* __restrict__ lw,   // [384]
    const float* __restrict__ lb,   // [1]
    float* __restrict__ out) {      // [B]
  const int b = blockIdx.x;
  const int lane = threadIdx.x;
  float acc = 0.f;
#pragma unroll
  for (int i = 0; i < RES / 64; ++i) {
    const int idx = i * 64 + lane;
    acc = fmaf(res[b * RES + idx], lw[idx], acc);
  }
#pragma unroll
  for (int off = 32; off >= 1; off >>= 1) acc += __shfl_xor(acc, off, 64);
  if (lane == 0) out[b] = acc + lb[0];
}

extern "C" void kernel_launch(void* const* d_in, const int* in_sizes, int n_in,
                              void* d_out, int out_size, void* d_ws, size_t ws_size,
                              hipStream_t stream) {
  const float* x0 = (const float*)d_in[0];
  const float* W0 = (const float*)d_in[1];
  const float* b0 = (const float*)d_in[2];
  const float* W1 = (const float*)d_in[3];
  const float* b1 = (const float*)d_in[4];
  const float* W2 = (const float*)d_in[5];
  const float* b2 = (const float*)d_in[6];
  const float* lw = (const float*)d_in[7];
  const float* lb = (const float*)d_in[8];
  float* out = (float*)d_out;

  // workspace: h1 [512,128,64] f32, h2 [512,128,64] f32, res [512,384] f32
  float* h1 = (float*)d_ws;
  float* h2 = h1 + (size_t)Bb * Oo * Dd;
  float* res = h2 + (size_t)Bb * Oo * Dd;

  dim3 grid(Bb, 2), blk(256);
  cin_layer_kernel<32><<<grid, blk, 0, stream>>>(x0, x0, W0, b0, h1, res, 0);
  cin_layer_kernel<128><<<grid, blk, 0, stream>>>(x0, h1, W1, b1, h2, res, 128);
  cin_layer_kernel<128><<<grid, blk, 0, stream>>>(x0, h2, W2, b2, nullptr, res, 256);
  cin_score_kernel<<<dim3(Bb), dim3(64), 0, stream>>>(res, lw, lb, out);
}

// Round 2
// 463.324 us; speedup vs baseline: 2.5212x; 2.5212x over previous
//
#include <hip/hip_runtime.h>
#include <hip/hip_bf16.h>

// CIN via MFMA with 3-term bf16 split:
//   per layer: C[o, (b,d)] = W[o,k] @ Z[k,(b,d)],  Z[(hh,m),d] = h[b,hh,d]*x0[b,m,d]
//   W*Z ~= Whi*Zhi + Whi*Zlo + Wlo*Zhi  (error ~2^-18 relative per term)
// B=512, M=32, D=64, O=128 per layer, K = H*32 (1024 / 4096 / 4096).

constexpr int Bb = 512, Mm = 32, Dd = 64, Oo = 128, RES = 384;

typedef __attribute__((ext_vector_type(8))) short bf16x8;
typedef __attribute__((ext_vector_type(4))) float f32x4;

static __device__ __forceinline__ ushort f2bf(float f) {
  union { float f; uint u; } v;
  v.f = f;
  uint u = v.u;
  return (ushort)((u + 0x7FFFu + ((u >> 16) & 1u)) >> 16);  // RNE
}
static __device__ __forceinline__ float bf2f(ushort b) {
  union { uint u; float f; } v;
  v.u = (uint)b << 16;
  return v.f;
}

// Split W[o][k] fp32 into bf16 hi/lo planes, stored in MFMA A-fragment lane
// order: frag (s = k/32, f = o/16): elem[((s*8+f)*64 + lane)*8 + j] =
//   W[f*16 + (lane&15)][s*32 + (lane>>4)*8 + j]
__global__ __launch_bounds__(256) void wsplit_kernel(const float* __restrict__ W,
                                                     ushort* __restrict__ Whi,
                                                     ushort* __restrict__ Wlo, int K) {
  int t = blockIdx.x * 256 + threadIdx.x;
  int total = (K / 32) * 8 * 64;
  if (t >= total) return;
  int l = t & 63;
  int f = (t >> 6) & 7;
  int s = t >> 9;
  int o = f * 16 + (l & 15);
  int k0 = s * 32 + (l >> 4) * 8;
  const float* src = W + (size_t)o * K + k0;
  ushort hi[8], lo[8];
#pragma unroll
  for (int j = 0; j < 8; ++j) {
    float w = src[j];
    ushort h = f2bf(w);
    hi[j] = h;
    lo[j] = f2bf(w - bf2f(h));
  }
  *reinterpret_cast<uint4*>(Whi + (size_t)t * 8) = *reinterpret_cast<uint4*>(hi);
  *reinterpret_cast<uint4*>(Wlo + (size_t)t * 8) = *reinterpret_cast<uint4*>(lo);
}

template <int H>
__global__ __launch_bounds__(256, 2) void cin_mfma_kernel(
    const float* __restrict__ x0,    // [512,32,64]
    const float* __restrict__ h_in,  // [512,H,64]
    const ushort* __restrict__ Whi,  // frag-ordered bf16
    const ushort* __restrict__ Wlo,
    const float* __restrict__ bias,  // [128]
    float* __restrict__ h_out,       // [512,128,64] or nullptr
    float* __restrict__ res,         // [512,384]
    int res_off) {
  constexpr int K = H * 32;
  constexpr int NT = K / 128;  // k-tiles of 128

  // Z tile: [d=64][k_local=128] bf16 hi/lo, XOR-swizzled within each 256B row
  __shared__ ushort z_hi[64 * 128];
  __shared__ ushort z_lo[64 * 128];

  const int b = blockIdx.x;
  const int t = threadIdx.x;
  const int lane = t & 63;
  const int w = __builtin_amdgcn_readfirstlane(t >> 6);  // wave id (o-split)
  const int g2 = t >> 6;                                 // build row-group
  const int d = lane;

  // x0[b, m, d] cache: the 8 m-values this thread's build pairs need.
  float x_c[8];
#pragma unroll
  for (int i = 0; i < 8; ++i) {
    int m = (2 * g2 + 8 * (i >> 1) + (i & 1)) & 31;
    x_c[i] = x0[((size_t)b * 32 + m) * 64 + d];
  }

  f32x4 acc[2][4];
#pragma unroll
  for (int i = 0; i < 2; ++i)
#pragma unroll
    for (int j = 0; j < 4; ++j) acc[i][j] = (f32x4){0.f, 0.f, 0.f, 0.f};

  const float* hb = h_in + (size_t)b * H * 64;

#pragma unroll 1
  for (int kt = 0; kt < NT; ++kt) {
    // ---- build Z tile: rows k = kt*128 .. kt*128+127 ----
    float h_c[4];
#pragma unroll
    for (int q = 0; q < 4; ++q) h_c[q] = hb[(size_t)(kt * 4 + q) * 64 + d];

    if (kt > 0) __syncthreads();  // prev MFMA must finish before overwrite

#pragma unroll
    for (int jj = 0; jj < 16; ++jj) {
      int pp = g2 + 4 * jj;  // pair index: kk = 2*pp, 2*pp+1
      float hv = h_c[jj >> 2];
      float p0 = hv * x_c[(jj & 3) * 2 + 0];
      float p1 = hv * x_c[(jj & 3) * 2 + 1];
      ushort h0 = f2bf(p0), h1 = f2bf(p1);
      ushort l0 = f2bf(p0 - bf2f(h0)), l1 = f2bf(p1 - bf2f(h1));
      int byte = d * 256 + ((4 * pp) ^ ((d & 7) << 4));
      *reinterpret_cast<uint*>(reinterpret_cast<char*>(z_hi) + byte) =
          (uint)h0 | ((uint)h1 << 16);
      *reinterpret_cast<uint*>(reinterpret_cast<char*>(z_lo) + byte) =
          (uint)l0 | ((uint)l1 << 16);
    }
    __syncthreads();

    // ---- MFMA: 4 k-steps of 32 ----
#pragma unroll
    for (int sl = 0; sl < 4; ++sl) {
      int s = kt * 4 + sl;
      bf16x8 ah[2], al[2];
#pragma unroll
      for (int fo = 0; fo < 2; ++fo) {
        size_t aoff = ((size_t)(s * 8 + (w * 2 + fo)) * 64 + lane) * 8;
        ah[fo] = *reinterpret_cast<const bf16x8*>(Whi + aoff);
        al[fo] = *reinterpret_cast<const bf16x8*>(Wlo + aoff);
      }
      bf16x8 bh[4], bl[4];
#pragma unroll
      for (int fd = 0; fd < 4; ++fd) {
        int drow = fd * 16 + (lane & 15);
        int bk = sl * 64 + ((lane >> 4) << 4);
        int byte = drow * 256 + (bk ^ ((drow & 7) << 4));
        bh[fd] = *reinterpret_cast<const bf16x8*>(reinterpret_cast<char*>(z_hi) + byte);
        bl[fd] = *reinterpret_cast<const bf16x8*>(reinterpret_cast<char*>(z_lo) + byte);
      }
      // term 1: Whi*Zhi   (8 independent acc chains per term group)
#pragma unroll
      for (int fo = 0; fo < 2; ++fo)
#pragma unroll
        for (int fd = 0; fd < 4; ++fd)
          acc[fo][fd] = __builtin_amdgcn_mfma_f32_16x16x32_bf16(ah[fo], bh[fd],
                                                                acc[fo][fd], 0, 0, 0);
      // term 2: Whi*Zlo
#pragma unroll
      for (int fo = 0; fo < 2; ++fo)
#pragma unroll
        for (int fd = 0; fd < 4; ++fd)
          acc[fo][fd] = __builtin_amdgcn_mfma_f32_16x16x32_bf16(ah[fo], bl[fd],
                                                                acc[fo][fd], 0, 0, 0);
      // term 3: Wlo*Zhi
#pragma unroll
      for (int fo = 0; fo < 2; ++fo)
#pragma unroll
        for (int fd = 0; fd < 4; ++fd)
          acc[fo][fd] = __builtin_amdgcn_mfma_f32_16x16x32_bf16(al[fo], bh[fd],
                                                                acc[fo][fd], 0, 0, 0);
    }
  }

  // ---- epilogue: bias + relu, write h_out, reduce over d into res ----
  const int rgrp = lane >> 4;
  const int cid = lane & 15;
#pragma unroll
  for (int fo = 0; fo < 2; ++fo) {
#pragma unroll
    for (int r = 0; r < 4; ++r) {
      int o = w * 32 + fo * 16 + rgrp * 4 + r;
      float bs = bias[o];
      float sd = 0.f;
#pragma unroll
      for (int fd = 0; fd < 4; ++fd) {
        float v = acc[fo][fd][r] + bs;
        v = v > 0.f ? v : 0.f;
        if (h_out != nullptr) h_out[((size_t)b * 128 + o) * 64 + fd * 16 + cid] = v;
        sd += v;
      }
#pragma unroll
      for (int mk = 1; mk < 16; mk <<= 1) sd += __shfl_xor(sd, mk, 64);
      if (cid == 0) res[(size_t)b * RES + res_off + o] = sd;
    }
  }
}

__global__ __launch_bounds__(64) void cin_score_kernel(
    const float* __restrict__ res, const float* __restrict__ lw,
    const float* __restrict__ lb, float* __restrict__ out) {
  const int b = blockIdx.x;
  const int lane = threadIdx.x;
  float acc = 0.f;
#pragma unroll
  for (int i = 0; i < RES / 64; ++i) {
    const int idx = i * 64 + lane;
    acc = fmaf(res[b * RES + idx], lw[idx], acc);
  }
#pragma unroll
  for (int off = 32; off >= 1; off >>= 1) acc += __shfl_xor(acc, off, 64);
  if (lane == 0) out[b] = acc + lb[0];
}

extern "C" void kernel_launch(void* const* d_in, const int* in_sizes, int n_in,
                              void* d_out, int out_size, void* d_ws, size_t ws_size,
                              hipStream_t stream) {
  const float* x0 = (const float*)d_in[0];
  const float* W0 = (const float*)d_in[1];
  const float* b0 = (const float*)d_in[2];
  const float* W1 = (const float*)d_in[3];
  const float* b1 = (const float*)d_in[4];
  const float* W2 = (const float*)d_in[5];
  const float* b2 = (const float*)d_in[6];
  const float* lw = (const float*)d_in[7];
  const float* lb = (const float*)d_in[8];
  float* out = (float*)d_out;

  // workspace layout (all 16B-aligned by construction)
  float* h1 = (float*)d_ws;                         // 512*128*64 f32
  float* h2 = h1 + (size_t)Bb * Oo * Dd;            // 512*128*64 f32
  float* res = h2 + (size_t)Bb * Oo * Dd;           // 512*384 f32
  ushort* Whi0 = (ushort*)(res + (size_t)Bb * RES);
  ushort* Wlo0 = Whi0 + (size_t)128 * 1024;
  ushort* Whi1 = Wlo0 + (size_t)128 * 1024;
  ushort* Wlo1 = Whi1 + (size_t)128 * 4096;
  ushort* Whi2 = Wlo1 + (size_t)128 * 4096;
  ushort* Wlo2 = Whi2 + (size_t)128 * 4096;

  wsplit_kernel<<<dim3(64), dim3(256), 0, stream>>>(W0, Whi0, Wlo0, 1024);
  wsplit_kernel<<<dim3(256), dim3(256), 0, stream>>>(W1, Whi1, Wlo1, 4096);
  wsplit_kernel<<<dim3(256), dim3(256), 0, stream>>>(W2, Whi2, Wlo2, 4096);

  cin_mfma_kernel<32><<<dim3(Bb), dim3(256), 0, stream>>>(x0, x0, Whi0, Wlo0, b0, h1, res, 0);
  cin_mfma_kernel<128><<<dim3(Bb), dim3(256), 0, stream>>>(x0, h1, Whi1, Wlo1, b1, h2, res, 128);
  cin_mfma_kernel<128><<<dim3(Bb), dim3(256), 0, stream>>>(x0, h2, Whi2, Wlo2, b2, nullptr, res, 256);

  cin_score_kernel<<<dim3(Bb), dim3(64), 0, stream>>>(res, lw, lb, out);
}

// Round 3
// 274.166 us; speedup vs baseline: 4.2607x; 1.6899x over previous
//
#include <hip/hip_runtime.h>

// CIN factored: out[b,o,d] = relu(bias[o] + sum_hh h[b,hh,d] * Y_hh[o,d]),
//   Y_hh[o,d] = sum_m W[o,hh,m] * x0[b,m,d]   (MFMA, 3-term bf16 split on W,x0)
// The hh-sum runs in fp32 VALU on MFMA outputs; no Z materialization, no
// in-loop barriers. B=512, M=32, D=64, O=128/layer, H = 32/128/128.

constexpr int Bb = 512, Mm = 32, Dd = 64, Oo = 128, RES = 384;

typedef __attribute__((ext_vector_type(8))) short bf16x8;
typedef __attribute__((ext_vector_type(4))) float f32x4;

static __device__ __forceinline__ ushort f2bf(float f) {
  union { float f; uint u; } v;
  v.f = f;
  uint u = v.u;
  return (ushort)((u + 0x7FFFu + ((u >> 16) & 1u)) >> 16);  // RNE
}
static __device__ __forceinline__ float bf2f(ushort b) {
  union { uint u; float f; } v;
  v.u = (uint)b << 16;
  return v.f;
}

// W[o][hh*32+m] -> A-frag planes Wf[hh][f][lane][j]:
//   o = f*16 + (lane&15), m = (lane>>4)*8 + j
__global__ __launch_bounds__(256) void wsplit_kernel(const float* __restrict__ W,
                                                     ushort* __restrict__ Whi,
                                                     ushort* __restrict__ Wlo, int H) {
  int t = blockIdx.x * 256 + threadIdx.x;
  if (t >= H * 8 * 64) return;
  int l = t & 63, fo = (t >> 6) & 7, hh = t >> 9;
  int o = fo * 16 + (l & 15);
  int m0 = (l >> 4) * 8;
  const float* src = W + (size_t)o * (H * 32) + hh * 32 + m0;
  ushort hi[8], lo[8];
#pragma unroll
  for (int j = 0; j < 8; ++j) {
    float w = src[j];
    ushort h = f2bf(w);
    hi[j] = h;
    lo[j] = f2bf(w - bf2f(h));
  }
  *reinterpret_cast<uint4*>(Whi + (size_t)t * 8) = *reinterpret_cast<uint4*>(hi);
  *reinterpret_cast<uint4*>(Wlo + (size_t)t * 8) = *reinterpret_cast<uint4*>(lo);
}

// x0[b][m][d] -> B-frag planes Xf[b][fd][lane][j]:
//   m = (lane>>4)*8 + j, d = fd*16 + (lane&15)
__global__ __launch_bounds__(256) void x0split_kernel(const float* __restrict__ x0,
                                                      ushort* __restrict__ Xhi,
                                                      ushort* __restrict__ Xlo) {
  int t = blockIdx.x * 256 + threadIdx.x;  // 512*4*64
  int l = t & 63, fd = (t >> 6) & 3, b = t >> 8;
  int d = fd * 16 + (l & 15);
  int m0 = (l >> 4) * 8;
  const float* src = x0 + ((size_t)b * Mm + m0) * Dd + d;
  ushort hi[8], lo[8];
#pragma unroll
  for (int j = 0; j < 8; ++j) {
    float w = src[j * Dd];
    ushort h = f2bf(w);
    hi[j] = h;
    lo[j] = f2bf(w - bf2f(h));
  }
  *reinterpret_cast<uint4*>(Xhi + (size_t)t * 8) = *reinterpret_cast<uint4*>(hi);
  *reinterpret_cast<uint4*>(Xlo + (size_t)t * 8) = *reinterpret_cast<uint4*>(lo);
}

template <int H>
__global__ __launch_bounds__(256, 4) void cin_mfma_kernel(
    const float* __restrict__ h_in,   // [512,H,64] fp32
    const ushort* __restrict__ Whi,   // [H][8][64][8]
    const ushort* __restrict__ Wlo,
    const ushort* __restrict__ Xhi,   // [512][4][64][8]
    const ushort* __restrict__ Xlo,
    const float* __restrict__ bias,   // [128]
    float* __restrict__ h_out,        // [512,128,64] or nullptr
    float* __restrict__ res,          // [512,384]
    int res_off) {
  __shared__ float h_lds[H * Dd];

  const int b = blockIdx.x;
  const int q = blockIdx.y;  // o-half
  const int t = threadIdx.x;
  const int lane = t & 63;
  const int f = __builtin_amdgcn_readfirstlane(q * 4 + (t >> 6));  // A-frag idx
  const int cid = lane & 15;

  // stage h[b] into LDS (fp32, coalesced float4)
  {
    const float4* hg = reinterpret_cast<const float4*>(h_in + (size_t)b * H * Dd);
    float4* hl = reinterpret_cast<float4*>(h_lds);
#pragma unroll
    for (int i = 0; i < H * Dd / 4 / 256; ++i) hl[t + i * 256] = hg[t + i * 256];
  }

  // x0 B-fragments, resident in registers for the whole kernel
  bf16x8 xh[4], xl[4];
#pragma unroll
  for (int fd = 0; fd < 4; ++fd) {
    size_t off = (((size_t)b * 4 + fd) * 64 + lane) * 8;
    xh[fd] = *reinterpret_cast<const bf16x8*>(Xhi + off);
    xl[fd] = *reinterpret_cast<const bf16x8*>(Xlo + off);
  }

  __syncthreads();

  const f32x4 kZ = {0.f, 0.f, 0.f, 0.f};
  f32x4 acc[4];
#pragma unroll
  for (int fd = 0; fd < 4; ++fd) acc[fd] = kZ;

  const size_t hstride = (size_t)8 * 64 * 8;  // ushorts per hh
  const ushort* pwh = Whi + ((size_t)f * 64 + lane) * 8;
  const ushort* pwl = Wlo + ((size_t)f * 64 + lane) * 8;

  auto step = [&](int hh, bf16x8 ah, bf16x8 al) {
    float hv[4];
#pragma unroll
    for (int fd = 0; fd < 4; ++fd) hv[fd] = h_lds[hh * Dd + fd * 16 + cid];
    f32x4 y[4];
#pragma unroll
    for (int fd = 0; fd < 4; ++fd)
      y[fd] = __builtin_amdgcn_mfma_f32_16x16x32_bf16(ah, xh[fd], kZ, 0, 0, 0);
#pragma unroll
    for (int fd = 0; fd < 4; ++fd)
      y[fd] = __builtin_amdgcn_mfma_f32_16x16x32_bf16(ah, xl[fd], y[fd], 0, 0, 0);
#pragma unroll
    for (int fd = 0; fd < 4; ++fd)
      y[fd] = __builtin_amdgcn_mfma_f32_16x16x32_bf16(al, xh[fd], y[fd], 0, 0, 0);
#pragma unroll
    for (int fd = 0; fd < 4; ++fd)
#pragma unroll
      for (int r = 0; r < 4; ++r) acc[fd][r] = fmaf(hv[fd], y[fd][r], acc[fd][r]);
  };

  bf16x8 a0h = *reinterpret_cast<const bf16x8*>(pwh);
  bf16x8 a0l = *reinterpret_cast<const bf16x8*>(pwl);
#pragma unroll 1
  for (int hh = 0; hh < H; hh += 2) {
    bf16x8 a1h = *reinterpret_cast<const bf16x8*>(pwh + (size_t)(hh + 1) * hstride);
    bf16x8 a1l = *reinterpret_cast<const bf16x8*>(pwl + (size_t)(hh + 1) * hstride);
    step(hh, a0h, a0l);
    if (hh + 2 < H) {
      a0h = *reinterpret_cast<const bf16x8*>(pwh + (size_t)(hh + 2) * hstride);
      a0l = *reinterpret_cast<const bf16x8*>(pwl + (size_t)(hh + 2) * hstride);
    }
    step(hh + 1, a1h, a1l);
  }

  // epilogue: bias + relu, write h_out, reduce over d into res
  const int rg = lane >> 4;
#pragma unroll
  for (int r = 0; r < 4; ++r) {
    int o = f * 16 + rg * 4 + r;  // global o (= q*64 + w*16 + rg*4 + r)
    float bs = bias[o];
    float sd = 0.f;
#pragma unroll
    for (int fd = 0; fd < 4; ++fd) {
      float v = acc[fd][r] + bs;
      v = v > 0.f ? v : 0.f;
      if (h_out != nullptr) h_out[((size_t)b * Oo + o) * Dd + fd * 16 + cid] = v;
      sd += v;
    }
#pragma unroll
    for (int mk = 1; mk < 16; mk <<= 1) sd += __shfl_xor(sd, mk, 64);
    if (cid == 0) res[(size_t)b * RES + res_off + o] = sd;
  }
}

__global__ __launch_bounds__(64) void cin_score_kernel(
    const float* __restrict__ res, const float* __restrict__ lw,
    const float* __restrict__ lb, float* __restrict__ out) {
  const int b = blockIdx.x;
  const int lane = threadIdx.x;
  float acc = 0.f;
#pragma unroll
  for (int i = 0; i < RES / 64; ++i) {
    const int idx = i * 64 + lane;
    acc = fmaf(res[b * RES + idx], lw[idx], acc);
  }
#pragma unroll
  for (int off = 32; off >= 1; off >>= 1) acc += __shfl_xor(acc, off, 64);
  if (lane == 0) out[b] = acc + lb[0];
}

extern "C" void kernel_launch(void* const* d_in, const int* in_sizes, int n_in,
                              void* d_out, int out_size, void* d_ws, size_t ws_size,
                              hipStream_t stream) {
  const float* x0 = (const float*)d_in[0];
  const float* W0 = (const float*)d_in[1];
  const float* b0 = (const float*)d_in[2];
  const float* W1 = (const float*)d_in[3];
  const float* b1 = (const float*)d_in[4];
  const float* W2 = (const float*)d_in[5];
  const float* b2 = (const float*)d_in[6];
  const float* lw = (const float*)d_in[7];
  const float* lb = (const float*)d_in[8];
  float* out = (float*)d_out;

  float* h1 = (float*)d_ws;                // 512*128*64 f32 (16 MiB)
  float* h2 = h1 + (size_t)Bb * Oo * Dd;   // 16 MiB
  float* res = h2 + (size_t)Bb * Oo * Dd;  // 512*384 f32
  ushort* Whi0 = (ushort*)(res + (size_t)Bb * RES);
  ushort* Wlo0 = Whi0 + (size_t)32 * 8 * 64 * 8;
  ushort* Whi1 = Wlo0 + (size_t)32 * 8 * 64 * 8;
  ushort* Wlo1 = Whi1 + (size_t)128 * 8 * 64 * 8;
  ushort* Whi2 = Wlo1 + (size_t)128 * 8 * 64 * 8;
  ushort* Wlo2 = Whi2 + (size_t)128 * 8 * 64 * 8;
  ushort* Xhi = Wlo2 + (size_t)128 * 8 * 64 * 8;
  ushort* Xlo = Xhi + (size_t)Bb * 4 * 64 * 8;

  wsplit_kernel<<<dim3(64), dim3(256), 0, stream>>>(W0, Whi0, Wlo0, 32);
  wsplit_kernel<<<dim3(256), dim3(256), 0, stream>>>(W1, Whi1, Wlo1, 128);
  wsplit_kernel<<<dim3(256), dim3(256), 0, stream>>>(W2, Whi2, Wlo2, 128);
  x0split_kernel<<<dim3(512), dim3(256), 0, stream>>>(x0, Xhi, Xlo);

  cin_mfma_kernel<32><<<dim3(Bb, 2), dim3(256), 0, stream>>>(x0, Whi0, Wlo0, Xhi, Xlo, b0, h1, res, 0);
  cin_mfma_kernel<128><<<dim3(Bb, 2), dim3(256), 0, stream>>>(h1, Whi1, Wlo1, Xhi, Xlo, b1, h2, res, 128);
  cin_mfma_kernel<128><<<dim3(Bb, 2), dim3(256), 0, stream>>>(h2, Whi2, Wlo2, Xhi, Xlo, b2, nullptr, res, 256);

  cin_score_kernel<<<dim3(Bb), dim3(64), 0, stream>>>(res, lw, lb, out);
}